// Round 9
// baseline (194.758 us; speedup 1.0000x reference)
//
#include <hip/hip_runtime.h>
#include <math.h>

#define HH 128
#define WW 128
#define CC 64
#define BB 8
#define OC 64
#define OFFC 18
#define HW (HH*WW)
#define HP 136
#define WP 136
#define PHW (HP*WP)   /* 18496 */

typedef __attribute__((ext_vector_type(8))) _Float16 f16x8;
typedef __attribute__((ext_vector_type(4))) float f32x4;

// ws layout (floats):
//   P16:    8 img * 8 groups * PHW uint4 (8 fp16 ch each) = BB*32*PHW floats
//   offs:   (retained in layout, now unused)
//   wA_reg: 36864 fp16 (18432 fl) A-frag [(tap*2+kk)*64+o][quad][8j]
//   wA_off: 18432 fp16 (9216 fl)  [(tap*2+kk)*32+o][quad][8j], rows 18..31 zero
#define P_OFF      0
#define P_SIZE     (BB*32*PHW)
#define OFFS_OFF   (P_OFF + P_SIZE)
#define OFFS_SIZE  (BB*OFFC*HW)
#define WAREG_OFF  (OFFS_OFF + OFFS_SIZE)
#define WAREG_SIZE 18432
#define WAOFF_OFF  (WAREG_OFF + WAREG_SIZE)

#define PAD_BLOCKS 4624   /* BB*8*PHW / 256 */
#define PREP_BLOCKS 144

__device__ __forceinline__ unsigned short f2h(float f) {
    _Float16 t = (_Float16)f;
    unsigned short s;
    __builtin_memcpy(&s, &t, 2);
    return s;
}
__device__ __forceinline__ f16x8 u4_to_h8(uint4 u) {
    union { uint4 u; f16x8 h; } c; c.u = u; return c.h;
}
__device__ __forceinline__ f16x8 splat8(float f) {
    _Float16 t = (_Float16)f;
    return (f16x8){t, t, t, t, t, t, t, t};
}

// merged prep (weight repack) + pad (fp16 zero-padded P) — one launch.
__global__ __launch_bounds__(256) void prep_pad_kernel(
    const float* __restrict__ x, uint4* __restrict__ P,
    const float* __restrict__ w_reg, const float* __restrict__ w_off,
    unsigned short* __restrict__ wA_reg, unsigned short* __restrict__ wA_off)
{
    int bid = blockIdx.x;
    int tid = threadIdx.x;
    if (bid < PAD_BLOCKS) {
        int idx = bid * 256 + tid;                // over BB*8*PHW
        int pos = idx % PHW;
        int ig  = idx / PHW;          // img*8 + g
        int r   = pos / WP;
        int col = pos % WP;
        union { uint4 u; f16x8 h; } cv;
        cv.u = make_uint4(0u, 0u, 0u, 0u);
        if (r >= 4 && r <= 131 && col >= 4 && col <= 131) {
            const float* src = x + (ig * 8) * HW + (r - 4) * WW + (col - 4);
            #pragma unroll
            for (int e = 0; e < 8; ++e)
                cv.h[e] = (_Float16)src[e * HW];
        }
        P[idx] = cv.u;
    } else {
        int i = (bid - PAD_BLOCKS) * 256 + tid;
        if (i < 18 * 64 * 32) {
            int j = i & 7, quad = (i >> 3) & 3, o = (i >> 5) & 63, ks = i >> 11;
            int kt = ks >> 1, kk = ks & 1;
            int c = kk * 32 + quad * 8 + j;
            wA_reg[i] = f2h(w_reg[o * 576 + c * 9 + kt]);
        }
        if (i < 18 * 32 * 32) {
            int j = i & 7, quad = (i >> 3) & 3, o = (i >> 5) & 31, ks = i >> 10;
            int kt = ks >> 1, kk = ks & 1;
            int c = kk * 32 + quad * 8 + j;
            float v = (o < OFFC) ? w_off[(o * CC + c) * 9 + kt] : 0.0f;
            wA_off[i] = f2h(v);
        }
    }
}

struct Gather8 {
    uint4 a00, a01, a10, a11;   // first group pointer
    uint4 b00, b01, b10, b11;   // second group pointer
    float wx1, wy1;
};

__device__ __forceinline__ Gather8 issue_tap(
    const uint4* __restrict__ xq0, const uint4* __restrict__ xq1,
    int wv, int hv, int dx, int dy, float offx, float offy)
{
    const float scale = 129.0f / 127.0f;
    float pxf = ((float)wv + (float)dx) + offx;
    float pyf = ((float)hv + (float)dy) + offy;
    float qx = fminf(fmaxf(pxf * scale, -100.0f), 300.0f);
    float qy = fminf(fmaxf(pyf * scale, -100.0f), 300.0f);
    float x0f = floorf(qx), y0f = floorf(qy);
    Gather8 g;
    g.wx1 = qx - x0f;
    g.wy1 = qy - y0f;
    int ix0 = (int)x0f, iy0 = (int)y0f;
    int c0 = min(max(ix0 + 3, 0), WP - 2);
    int r0 = min(max(iy0 + 3, 0), HP - 1);
    int r1 = min(max(iy0 + 4, 0), HP - 1);
    int pr0 = r0 * WP + c0, pr1 = r1 * WP + c0;
    g.a00 = xq0[pr0]; g.a01 = xq0[pr0 + 1];
    g.a10 = xq0[pr1]; g.a11 = xq0[pr1 + 1];
    g.b00 = xq1[pr0]; g.b01 = xq1[pr0 + 1];
    g.b10 = xq1[pr1]; g.b11 = xq1[pr1 + 1];
    return g;
}

// Fused kernel, barrier-free main loop.
// Wave w owns a 16-px tile: lane = pixel(l&15) x ch-group(l>>4). Each lane
// gathers+blends ITS OWN MFMA B-fragment (B0 = ch (l>>4)*8, B1 = ch 32+(l>>4)*8)
// -> no LDS transpose, no barriers, waves fully independent. Same gather/blend/
// MFMA counts and accumulation order as the verified round-4 kernel
// (bit-identical output). LDS (17.3 KB) used only by the conv prologue.
// launch_bounds(256,4): VGPR cap 128 — the proven spill-free tier (r5/7/8:
// every tier above 4 blocks/CU spills the gather live set -> 1.5-2.3x slower).
__global__ __launch_bounds__(256, 4) void fused_deform_kernel(
    const uint4* __restrict__ P, const unsigned short* __restrict__ wA_off,
    const float* __restrict__ b_off, const unsigned short* __restrict__ wA_reg,
    const float* __restrict__ b_reg, float* __restrict__ out)
{
    __shared__ uint4 shbuf[3 * 4 * 66];        // 12672 B, conv staging only
    __shared__ float offs_lds[OFFC * 64];      // 4608 B
    int img  = blockIdx.x & 7;
    int rest = blockIdx.x >> 3;                // 0..255
    int half = rest & 1;
    int pblk = rest >> 1;                      // row 0..127
    int tid  = threadIdx.x;
    int lane = tid & 63;
    int wvid = tid >> 6;
    int hv = pblk;

    // ---- conv prologue: offset conv in two group-half passes (kk = K-half)
    // output px wv needs P cols wv+dx+3 (dx 0..2) -> base col half*64 + 3
    {
        int s2  = wvid & 1;                    // o-strip
        int ph2 = wvid >> 1;                   // 32-px half
        const f16x8* wOv = (const f16x8*)wA_off;
        f32x4 oacc[2];
        oacc[0] = (f32x4){0.f, 0.f, 0.f, 0.f};
        oacc[1] = (f32x4){0.f, 0.f, 0.f, 0.f};
        for (int kk = 0; kk < 2; ++kk) {
            for (int i = tid; i < 3 * 4 * 66; i += 256) {
                int r   = i / 264;
                int rem = i - r * 264;
                int gl  = rem / 66;
                int j   = rem - gl * 66;
                shbuf[(r * 4 + gl) * 66 + j] =
                    P[(img * 8 + kk * 4 + gl) * PHW + (pblk + 3 + r) * WP + (half * 64 + 3 + j)];
            }
            __syncthreads();
            const f16x8* xsc = (const f16x8*)shbuf;
            for (int tap = 0; tap < 9; ++tap) {
                int dy = tap / 3, dx = tap % 3;
                f16x8 a = wOv[((tap * 2 + kk) * 32 + s2 * 16 + (lane & 15)) * 4 + (lane >> 4)];
                #pragma unroll
                for (int pt = 0; pt < 2; ++pt) {
                    int sj = ph2 * 32 + pt * 16 + (lane & 15) + dx;
                    f16x8 b = xsc[(dy * 4 + (lane >> 4)) * 66 + sj];
                    oacc[pt] = __builtin_amdgcn_mfma_f32_16x16x32_f16(a, b, oacc[pt], 0, 0, 0);
                }
            }
            __syncthreads();   // reads done before restage
        }
        #pragma unroll
        for (int r = 0; r < 4; ++r) {
            int o = s2 * 16 + (lane >> 4) * 4 + r;
            if (o < OFFC) {
                float bias = b_off[o];
                #pragma unroll
                for (int pt = 0; pt < 2; ++pt) {
                    int p = ph2 * 32 + pt * 16 + (lane & 15);
                    offs_lds[o * 64 + p] = oacc[pt][r] + bias;
                }
            }
        }
    }
    __syncthreads();   // offs_lds ready; no further LDS writes -> no more barriers

    // ---- barrier-free deform main loop
    const f16x8* wAv = (const f16x8*)wA_reg;
    int pxi  = lane & 15;                  // pixel within this wave's 16-px tile
    int cg   = lane >> 4;                  // channel-group / k-quad
    int wvpx = wvid * 16 + pxi;            // px within the 64-px block
    int wcol = half * 64 + wvpx;           // global col
    const uint4* xqA = P + (img * 8 + cg) * PHW;       // k-half 0 channels
    const uint4* xqB = P + (img * 8 + cg + 4) * PHW;   // k-half 1 channels

    f32x4 acc[4];
    #pragma unroll
    for (int ot = 0; ot < 4; ++ot) acc[ot] = (f32x4){0.f, 0.f, 0.f, 0.f};

    for (int tap = 0; tap < 9; ++tap) {
        float ox = offs_lds[(2 * tap + 0) * 64 + wvpx];
        float oy = offs_lds[(2 * tap + 1) * 64 + wvpx];
        Gather8 g = issue_tap(xqA, xqB, wcol, hv, tap % 3 - 1, tap / 3 - 1, ox, oy);

        f16x8 wx1v = splat8(g.wx1), wx0v = splat8(1.0f - g.wx1);
        f16x8 wy1v = splat8(g.wy1), wy0v = splat8(1.0f - g.wy1);
        f16x8 r0a = u4_to_h8(g.a00) * wx0v + u4_to_h8(g.a01) * wx1v;
        f16x8 r1a = u4_to_h8(g.a10) * wx0v + u4_to_h8(g.a11) * wx1v;
        f16x8 B0  = r0a * wy0v + r1a * wy1v;            // this lane's B-frag, k-half 0
        f16x8 r0b = u4_to_h8(g.b00) * wx0v + u4_to_h8(g.b01) * wx1v;
        f16x8 r1b = u4_to_h8(g.b10) * wx0v + u4_to_h8(g.b11) * wx1v;
        f16x8 B1  = r0b * wy0v + r1b * wy1v;            // k-half 1

        #pragma unroll
        for (int ot = 0; ot < 4; ++ot) {
            f16x8 a0 = wAv[((tap * 2 + 0) * 64 + ot * 16 + pxi) * 4 + cg];
            f16x8 a1 = wAv[((tap * 2 + 1) * 64 + ot * 16 + pxi) * 4 + cg];
            acc[ot] = __builtin_amdgcn_mfma_f32_16x16x32_f16(a0, B0, acc[ot], 0, 0, 0);
            acc[ot] = __builtin_amdgcn_mfma_f32_16x16x32_f16(a1, B1, acc[ot], 0, 0, 0);
        }
    }

    // C-write: D layout col=lane&15 (pixel), row=(lane>>4)*4+r (o within tile)
    float* op = out + img * (OC * HW) + hv * WW + half * 64 + wvid * 16;
    #pragma unroll
    for (int ot = 0; ot < 4; ++ot) {
        #pragma unroll
        for (int r = 0; r < 4; ++r) {
            int o = ot * 16 + cg * 4 + r;
            op[o * HW + pxi] = acc[ot][r] + b_reg[o];
        }
    }
}

extern "C" void kernel_launch(void* const* d_in, const int* in_sizes, int n_in,
                              void* d_out, int out_size, void* d_ws, size_t ws_size,
                              hipStream_t stream) {
    const float* x     = (const float*)d_in[0];
    const float* w_off = (const float*)d_in[1];
    const float* b_off = (const float*)d_in[2];
    const float* w_reg = (const float*)d_in[3];
    const float* b_reg = (const float*)d_in[4];
    float* out = (float*)d_out;
    float* ws  = (float*)d_ws;

    uint4* P      = (uint4*)(ws + P_OFF);
    unsigned short* wA_reg = (unsigned short*)(ws + WAREG_OFF);
    unsigned short* wA_off = (unsigned short*)(ws + WAOFF_OFF);

    prep_pad_kernel<<<PAD_BLOCKS + PREP_BLOCKS, 256, 0, stream>>>(
        x, P, w_reg, w_off, wA_reg, wA_off);
    fused_deform_kernel<<<2048, 256, 0, stream>>>(
        P, wA_off, b_off, wA_reg, b_reg, out);
}

// Round 11
// 146.301 us; speedup vs baseline: 1.3312x; 1.3312x over previous
//
#include <hip/hip_runtime.h>
#include <math.h>

// NOTE (R9 post-mortem): fused_deform is bound by per-CU vector-memory REQUEST
// throughput: ~544 line-requests/block-tap x 9 taps x 8 blocks/CU x ~4cyc/req
// = ~156K cyc = ~65us == measured 66.7us. Prefetch (R2), occupancy 33->77%
// (R5/7/8/9), and barrier removal (R9) were all null-to-negative because none
// reduce requests. R4's 64-px-dense 16B gathers are at the max merge rate
// (~4 lanes/request); fp16 granularity makes this the request floor.

#define HH 128
#define WW 128
#define CC 64
#define BB 8
#define OC 64
#define OFFC 18
#define HW (HH*WW)
#define HP 136
#define WP 136
#define PHW (HP*WP)   /* 18496 */

typedef __attribute__((ext_vector_type(8))) _Float16 f16x8;
typedef __attribute__((ext_vector_type(4))) float f32x4;

// ws layout (floats):
//   P16:    8 img * 8 groups * PHW uint4 (8 fp16 ch each) = BB*32*PHW floats
//   offs:   (retained in layout, now unused)
//   wA_reg: 36864 fp16 (18432 fl) A-frag [(tap*2+kk)*64+o][quad][8j]
//   wA_off: 18432 fp16 (9216 fl)  [(tap*2+kk)*32+o][quad][8j], rows 18..31 zero
#define P_OFF      0
#define P_SIZE     (BB*32*PHW)
#define OFFS_OFF   (P_OFF + P_SIZE)
#define OFFS_SIZE  (BB*OFFC*HW)
#define WAREG_OFF  (OFFS_OFF + OFFS_SIZE)
#define WAREG_SIZE 18432
#define WAOFF_OFF  (WAREG_OFF + WAREG_SIZE)

#define PAD_BLOCKS 4624   /* BB*8*PHW / 256 */
#define PREP_BLOCKS 144

__device__ __forceinline__ unsigned short f2h(float f) {
    _Float16 t = (_Float16)f;
    unsigned short s;
    __builtin_memcpy(&s, &t, 2);
    return s;
}
__device__ __forceinline__ f16x8 u4_to_h8(uint4 u) {
    union { uint4 u; f16x8 h; } c; c.u = u; return c.h;
}
__device__ __forceinline__ uint4 h8_to_u4(f16x8 h) {
    union { uint4 u; f16x8 h; } c; c.h = h; return c.u;
}
__device__ __forceinline__ f16x8 splat8(float f) {
    _Float16 t = (_Float16)f;
    return (f16x8){t, t, t, t, t, t, t, t};
}

// merged prep (weight repack) + pad (fp16 zero-padded P) — one launch.
__global__ __launch_bounds__(256) void prep_pad_kernel(
    const float* __restrict__ x, uint4* __restrict__ P,
    const float* __restrict__ w_reg, const float* __restrict__ w_off,
    unsigned short* __restrict__ wA_reg, unsigned short* __restrict__ wA_off)
{
    int bid = blockIdx.x;
    int tid = threadIdx.x;
    if (bid < PAD_BLOCKS) {
        int idx = bid * 256 + tid;                // over BB*8*PHW
        int pos = idx % PHW;
        int ig  = idx / PHW;                      // img*8 + g
        int r   = pos / WP;
        int col = pos % WP;
        union { uint4 u; f16x8 h; } cv;
        cv.u = make_uint4(0u, 0u, 0u, 0u);
        if (r >= 4 && r <= 131 && col >= 4 && col <= 131) {
            const float* src = x + (ig * 8) * HW + (r - 4) * WW + (col - 4);
            #pragma unroll
            for (int e = 0; e < 8; ++e)
                cv.h[e] = (_Float16)src[e * HW];
        }
        P[idx] = cv.u;
    } else {
        int i = (bid - PAD_BLOCKS) * 256 + tid;
        if (i < 18 * 64 * 32) {
            int j = i & 7, quad = (i >> 3) & 3, o = (i >> 5) & 63, ks = i >> 11;
            int kt = ks >> 1, kk = ks & 1;
            int c = kk * 32 + quad * 8 + j;
            wA_reg[i] = f2h(w_reg[o * 576 + c * 9 + kt]);
        }
        if (i < 18 * 32 * 32) {
            int j = i & 7, quad = (i >> 3) & 3, o = (i >> 5) & 31, ks = i >> 10;
            int kt = ks >> 1, kk = ks & 1;
            int c = kk * 32 + quad * 8 + j;
            float v = (o < OFFC) ? w_off[(o * CC + c) * 9 + kt] : 0.0f;
            wA_off[i] = f2h(v);
        }
    }
}

struct Gather8 {
    uint4 a00, a01, a10, a11;   // group qp*2
    uint4 b00, b01, b10, b11;   // group qp*2+1
    float wx1, wy1;
};

__device__ __forceinline__ Gather8 issue_tap(
    const uint4* __restrict__ xq0, const uint4* __restrict__ xq1,
    int wv, int hv, int dx, int dy, float offx, float offy)
{
    const float scale = 129.0f / 127.0f;
    float pxf = ((float)wv + (float)dx) + offx;
    float pyf = ((float)hv + (float)dy) + offy;
    float qx = fminf(fmaxf(pxf * scale, -100.0f), 300.0f);
    float qy = fminf(fmaxf(pyf * scale, -100.0f), 300.0f);
    float x0f = floorf(qx), y0f = floorf(qy);
    Gather8 g;
    g.wx1 = qx - x0f;
    g.wy1 = qy - y0f;
    int ix0 = (int)x0f, iy0 = (int)y0f;
    int c0 = min(max(ix0 + 3, 0), WP - 2);
    int r0 = min(max(iy0 + 3, 0), HP - 1);
    int r1 = min(max(iy0 + 4, 0), HP - 1);
    int pr0 = r0 * WP + c0, pr1 = r1 * WP + c0;
    g.a00 = xq0[pr0]; g.a01 = xq0[pr0 + 1];
    g.a10 = xq0[pr1]; g.a11 = xq0[pr1 + 1];
    g.b00 = xq1[pr0]; g.b01 = xq1[pr0 + 1];
    g.b10 = xq1[pr1]; g.b11 = xq1[pr1 + 1];
    return g;
}

__device__ __forceinline__ void blend_write(
    uint4* __restrict__ dst, int qp, int pxl, const Gather8& g)
{
    f16x8 wx1v = splat8(g.wx1), wx0v = splat8(1.0f - g.wx1);
    f16x8 wy1v = splat8(g.wy1), wy0v = splat8(1.0f - g.wy1);
    f16x8 r0a = u4_to_h8(g.a00) * wx0v + u4_to_h8(g.a01) * wx1v;
    f16x8 r1a = u4_to_h8(g.a10) * wx0v + u4_to_h8(g.a11) * wx1v;
    dst[(qp * 2 + 0) * 64 + pxl] = h8_to_u4(r0a * wy0v + r1a * wy1v);
    f16x8 r0b = u4_to_h8(g.b00) * wx0v + u4_to_h8(g.b01) * wx1v;
    f16x8 r1b = u4_to_h8(g.b10) * wx0v + u4_to_h8(g.b11) * wx1v;
    dst[(qp * 2 + 1) * 64 + pxl] = h8_to_u4(r0b * wy0v + r1b * wy1v);
}

// Fused: per-block offset conv (3x66-col strip, 36 MFMA/wave) -> offs in LDS ->
// pipelined deform main loop (identical numerics to verified kernel; offsets
// come from LDS instead of a global round-trip). Verified at 66.7us (round 4).
__global__ __launch_bounds__(256, 4) void fused_deform_kernel(
    const uint4* __restrict__ P, const unsigned short* __restrict__ wA_off,
    const float* __restrict__ b_off, const unsigned short* __restrict__ wA_reg,
    const float* __restrict__ b_reg, float* __restrict__ out)
{
    __shared__ uint4 shbuf[3 * 8 * 66];        // 25344 B: stage, then xs2 ping-pong
    __shared__ float offs_lds[OFFC * 64];      // 4608 B
    int img  = blockIdx.x & 7;
    int rest = blockIdx.x >> 3;                // 0..255
    int half = rest & 1;
    int pblk = rest >> 1;                      // row 0..127
    int tid  = threadIdx.x;
    int pxl  = tid & 63;                       // local px
    int qp   = tid >> 6;                       // group pair 0..3
    int lane = tid & 63;
    int wvid = tid >> 6;
    int wv = half * 64 + pxl;
    int hv = pblk;

    // ---- phase 1: stage 3 rows x 66 cols x 8 groups of P for the offset conv
    // output px wv needs P cols wv+dx+3 (dx 0..2) -> base col half*64 + 3
    for (int i = tid; i < 3 * 8 * 66; i += 256) {
        int r   = i / 528;
        int rem = i - r * 528;
        int g   = rem / 66;
        int j   = rem - g * 66;
        shbuf[(r * 8 + g) * 66 + j] =
            P[(img * 8 + g) * PHW + (pblk + 3 + r) * WP + (half * 64 + 3 + j)];
    }
    __syncthreads();

    // ---- phase 2: offset conv for this block's 64 px, 18 out-ch, via MFMA
    {
        int s2  = wvid & 1;                    // o-strip
        int ph2 = wvid >> 1;                   // 32-px half
        const f16x8* wOv = (const f16x8*)wA_off;
        const f16x8* xsc = (const f16x8*)shbuf;
        f32x4 oacc[2];
        oacc[0] = (f32x4){0.f, 0.f, 0.f, 0.f};
        oacc[1] = (f32x4){0.f, 0.f, 0.f, 0.f};
        for (int tap = 0; tap < 9; ++tap) {
            int dy = tap / 3, dx = tap % 3;
            f16x8 a0 = wOv[((tap * 2 + 0) * 32 + s2 * 16 + (lane & 15)) * 4 + (lane >> 4)];
            f16x8 a1 = wOv[((tap * 2 + 1) * 32 + s2 * 16 + (lane & 15)) * 4 + (lane >> 4)];
            #pragma unroll
            for (int pt = 0; pt < 2; ++pt) {
                int sj = ph2 * 32 + pt * 16 + (lane & 15) + dx;
                f16x8 b0 = xsc[(dy * 8 + (lane >> 4)) * 66 + sj];
                oacc[pt] = __builtin_amdgcn_mfma_f32_16x16x32_f16(a0, b0, oacc[pt], 0, 0, 0);
                f16x8 b1 = xsc[(dy * 8 + 4 + (lane >> 4)) * 66 + sj];
                oacc[pt] = __builtin_amdgcn_mfma_f32_16x16x32_f16(a1, b1, oacc[pt], 0, 0, 0);
            }
        }
        #pragma unroll
        for (int r = 0; r < 4; ++r) {
            int o = s2 * 16 + (lane >> 4) * 4 + r;
            if (o < OFFC) {
                float bias = b_off[o];
                #pragma unroll
                for (int pt = 0; pt < 2; ++pt) {
                    int p = ph2 * 32 + pt * 16 + (lane & 15);
                    offs_lds[o * 64 + p] = oacc[pt][r] + bias;
                }
            }
        }
    }
    __syncthreads();   // offs_lds ready; staged strip dead -> shbuf reusable as xs2

    // ---- phase 3: pipelined deform main loop
    const f16x8* wAv = (const f16x8*)wA_reg;
    const uint4* xq0 = P + (img * 8 + qp * 2 + 0) * PHW;
    const uint4* xq1 = P + (img * 8 + qp * 2 + 1) * PHW;
    int aidx = (wvid * 16 + (lane & 15)) * 4 + (lane >> 4);

    f32x4 acc[4];
    #pragma unroll
    for (int pt = 0; pt < 4; ++pt) acc[pt] = (f32x4){0.f, 0.f, 0.f, 0.f};

    float ox = offs_lds[0 * 64 + pxl], oy = offs_lds[1 * 64 + pxl];
    Gather8 cur = issue_tap(xq0, xq1, wv, hv, -1, -1, ox, oy);
    f16x8 a0c = wAv[0 * 256 + aidx];
    f16x8 a1c = wAv[1 * 256 + aidx];

    #pragma unroll
    for (int tap = 0; tap < 9; ++tap) {
        // 1. blend current corners (vmcnt wait auto-inserted at use), write LDS
        uint4* dst = shbuf + (tap & 1) * 512;
        blend_write(dst, qp, pxl, cur);

        // 2. issue next tap's gathers + A-frags (stay in flight across barrier)
        Gather8 nxt;
        f16x8 a0n, a1n;
        if (tap < 8) {
            int dx1 = (tap + 1) % 3 - 1, dy1 = (tap + 1) / 3 - 1;
            float oxn = offs_lds[(2 * tap + 2) * 64 + pxl];
            float oyn = offs_lds[(2 * tap + 3) * 64 + pxl];
            nxt = issue_tap(xq0, xq1, wv, hv, dx1, dy1, oxn, oyn);
            a0n = wAv[((tap + 1) * 2 + 0) * 256 + aidx];
            a1n = wAv[((tap + 1) * 2 + 1) * 256 + aidx];
        }

        // 3. barrier: drain LDS ops only — in-flight global loads survive
        asm volatile("s_waitcnt lgkmcnt(0)" ::: "memory");
        __builtin_amdgcn_s_barrier();
        asm volatile("" ::: "memory");

        // 4. consume this tap's LDS tile: 16 MFMAs
        const f16x8* xsv = (const f16x8*)(shbuf + (tap & 1) * 512);
        #pragma unroll
        for (int pt = 0; pt < 4; ++pt) {
            int pxi = pt * 16 + (lane & 15);
            f16x8 b0 = xsv[(lane >> 4) * 64 + pxi];
            acc[pt] = __builtin_amdgcn_mfma_f32_16x16x32_f16(a0c, b0, acc[pt], 0, 0, 0);
            f16x8 b1 = xsv[(4 + (lane >> 4)) * 64 + pxi];
            acc[pt] = __builtin_amdgcn_mfma_f32_16x16x32_f16(a1c, b1, acc[pt], 0, 0, 0);
        }

        // 5. rotate pipeline registers (SSA — fully unrolled)
        if (tap < 8) {
            cur = nxt; a0c = a0n; a1c = a1n;
        }
    }

    float* op = out + img * (OC * HW) + hv * WW + half * 64;
    #pragma unroll
    for (int r = 0; r < 4; ++r) {
        int o = wvid * 16 + (lane >> 4) * 4 + r;
        float bias = b_reg[o];
        #pragma unroll
        for (int pt = 0; pt < 4; ++pt)
            op[o * HW + pt * 16 + (lane & 15)] = acc[pt][r] + bias;
    }
}

extern "C" void kernel_launch(void* const* d_in, const int* in_sizes, int n_in,
                              void* d_out, int out_size, void* d_ws, size_t ws_size,
                              hipStream_t stream) {
    const float* x     = (const float*)d_in[0];
    const float* w_off = (const float*)d_in[1];
    const float* b_off = (const float*)d_in[2];
    const float* w_reg = (const float*)d_in[3];
    const float* b_reg = (const float*)d_in[4];
    float* out = (float*)d_out;
    float* ws  = (float*)d_ws;

    uint4* P      = (uint4*)(ws + P_OFF);
    unsigned short* wA_reg = (unsigned short*)(ws + WAREG_OFF);
    unsigned short* wA_off = (unsigned short*)(ws + WAOFF_OFF);

    prep_pad_kernel<<<PAD_BLOCKS + PREP_BLOCKS, 256, 0, stream>>>(
        x, P, w_reg, w_off, wA_reg, wA_off);
    fused_deform_kernel<<<2048, 256, 0, stream>>>(
        P, wA_off, b_off, wA_reg, b_reg, out);
}